// Round 3
// baseline (539.502 us; speedup 1.0000x reference)
//
#include <hip/hip_runtime.h>
#include <hip/hip_bf16.h>

// ---------------------------------------------------------------------------
// LDS-staged direct 3x3 conv (pad=1), fused bias+ReLU, virtual concat of two
// inputs (CIN1 channels from in1, CIN2 from in2). One block = one batch x one
// 16x16 output tile; one thread = one output pixel, ALL COUT channels
// (identical math/mapping to the round-1 kernel that passed, but inputs come
// from an LDS-staged patch instead of scattered global loads).
// ---------------------------------------------------------------------------
template <int CIN1, int CIN2, int COUT, int STRIDE, int CCH>
__global__ __launch_bounds__(256) void convp_k(
    const float* __restrict__ in1, const float* __restrict__ in2,
    const float* __restrict__ w,    // [COUT][CIN1+CIN2][3][3]
    const float* __restrict__ bias, // [COUT]
    float* __restrict__ out,
    int Hin, int Win)
{
    constexpr int CIN = CIN1 + CIN2;
    constexpr int TO  = 16;
    constexpr int P   = TO * STRIDE + 2;  // staged patch dim
    constexpr int PX  = P + 1;            // odd row stride
    __shared__ float Xs[CCH][P][PX];

    const int Ho = Hin / STRIDE, Wo = Win / STRIDE;
    const int tpr = Wo / TO, tpc = Ho / TO;
    int bid = blockIdx.x;
    const int tx = bid % tpr; bid /= tpr;
    const int ty = bid % tpc; bid /= tpc;
    const int b  = bid;

    const int tid = threadIdx.x;
    const int lx  = tid & 15;
    const int ly  = tid >> 4;

    const int y0 = ty * TO * STRIDE - 1;
    const int x0 = tx * TO * STRIDE - 1;
    const int HW = Hin * Win;

    float acc[COUT];
#pragma unroll
    for (int co = 0; co < COUT; ++co) acc[co] = bias[co];

    for (int cc = 0; cc < CIN; cc += CCH) {
        __syncthreads();
        // cooperative stage of CCH channels' (P x P) patch
        for (int c = 0; c < CCH; ++c) {
            int ci = cc + c;
            const float* src = (CIN2 == 0 || ci < CIN1)
                ? in1 + (size_t)(b * CIN1 + ci) * HW
                : in2 + (size_t)(b * CIN2 + (ci - CIN1)) * HW;
            for (int e = tid; e < P * P; e += 256) {
                int py = e / P, px = e % P;
                int gy = y0 + py, gx = x0 + px;
                bool ok = ((unsigned)gy < (unsigned)Hin) && ((unsigned)gx < (unsigned)Win);
                Xs[c][py][px] = ok ? src[gy * Win + gx] : 0.0f;
            }
        }
        __syncthreads();
        // compute: per channel, read 3x3 window once, FMA into all couts
        for (int c = 0; c < CCH; ++c) {
            float win[9];
#pragma unroll
            for (int ky = 0; ky < 3; ++ky)
#pragma unroll
                for (int kx = 0; kx < 3; ++kx)
                    win[ky * 3 + kx] = Xs[c][ly * STRIDE + ky][lx * STRIDE + kx];
#pragma unroll
            for (int co = 0; co < COUT; ++co) {
                const float* wp = w + ((size_t)co * CIN + cc + c) * 9;
#pragma unroll
                for (int k = 0; k < 9; ++k)
                    acc[co] += win[k] * wp[k];
            }
        }
    }

    const int oy = ty * TO + ly;
    const int ox = tx * TO + lx;
#pragma unroll
    for (int co = 0; co < COUT; ++co)
        out[((size_t)(b * COUT + co) * Ho + oy) * Wo + ox] = fmaxf(acc[co], 0.0f);
}

// ---------------------------------------------------------------------------
// FC1: h[32,1024] = relu(xs[32,24576] @ fw1[1024,24576]^T + fb1)
// (round-1 verbatim: split-K 32 chunks of 768, 64-n tile per block)
// ---------------------------------------------------------------------------
#define FC1_K 24576
#define FC1_N 1024
#define FC1_M 32
#define FC1_KS 32   // k splits
#define FC1_KC 768  // k per split
#define FC1_KP 64   // k per phase
#define FC1_NT 64   // n per block

__global__ __launch_bounds__(256) void fc1_stage_k(
    const float* __restrict__ xs,   // [32][24576]
    const float* __restrict__ fw1,  // [1024][24576]
    float* __restrict__ part)       // [KS][32][1024]
{
    __shared__ __align__(16) float As[FC1_KP][36];
    __shared__ __align__(16) float Bs[FC1_KP][66];

    const int tid = threadIdx.x;
    const int n0 = blockIdx.x * FC1_NT;
    const int ks = blockIdx.y;
    const int k0 = ks * FC1_KC;
    const int lane = tid & 63;
    const int grp = tid >> 6;

    const int m4 = (tid & 7) * 4;
    const int n2 = (tid >> 3) * 2;

    float acc[4][2];
#pragma unroll
    for (int i = 0; i < 4; ++i)
#pragma unroll
        for (int j = 0; j < 2; ++j) acc[i][j] = 0.0f;

    for (int p = 0; p < FC1_KC / FC1_KP; ++p) {
        const int kc = k0 + p * FC1_KP;
#pragma unroll
        for (int r = 0; r < 8; ++r) {
            int m = grp * 8 + r;
            As[lane][m] = xs[(size_t)m * FC1_K + kc + lane];
        }
#pragma unroll
        for (int r = 0; r < 16; ++r) {
            int nl = grp * 16 + r;
            Bs[lane][nl] = fw1[(size_t)(n0 + nl) * FC1_K + kc + lane];
        }
        __syncthreads();
#pragma unroll 8
        for (int k = 0; k < FC1_KP; ++k) {
            float4 a = *(const float4*)&As[k][m4];
            float2 bv = *(const float2*)&Bs[k][n2];
            acc[0][0] += a.x * bv.x; acc[0][1] += a.x * bv.y;
            acc[1][0] += a.y * bv.x; acc[1][1] += a.y * bv.y;
            acc[2][0] += a.z * bv.x; acc[2][1] += a.z * bv.y;
            acc[3][0] += a.w * bv.x; acc[3][1] += a.w * bv.y;
        }
        __syncthreads();
    }
#pragma unroll
    for (int i = 0; i < 4; ++i)
#pragma unroll
        for (int j = 0; j < 2; ++j)
            part[((size_t)ks * FC1_M + (m4 + i)) * FC1_N + n0 + n2 + j] = acc[i][j];
}

__global__ __launch_bounds__(256) void fc1_reduce_k(
    const float* __restrict__ part, const float* __restrict__ fb1,
    float* __restrict__ h1)
{
    int idx = blockIdx.x * 256 + threadIdx.x; // 32768
    int n = idx & (FC1_N - 1);
    int m = idx >> 10;
    float s = fb1[n];
#pragma unroll
    for (int ks = 0; ks < FC1_KS; ++ks)
        s += part[((size_t)ks * FC1_M + m) * FC1_N + n];
    h1[idx] = fmaxf(s, 0.0f);
}

// ---------------------------------------------------------------------------
// FC2: h2[32,32] = relu(h1[32,1024] @ fw2[32,1024]^T + fb2). One block per m.
// ---------------------------------------------------------------------------
__global__ __launch_bounds__(256) void fc2_k(
    const float* __restrict__ h1, const float* __restrict__ fw2,
    const float* __restrict__ fb2, float* __restrict__ h2)
{
    __shared__ float hs[1024];
    const int m = blockIdx.x;
    const int tid = threadIdx.x;
    for (int i = tid; i < 1024; i += 256) hs[i] = h1[m * 1024 + i];
    __syncthreads();
    const int wave = tid >> 6, lane = tid & 63;
#pragma unroll 1
    for (int nn = 0; nn < 8; ++nn) {
        int n = wave * 8 + nn;
        float p = 0.0f;
        for (int k = lane; k < 1024; k += 64)
            p += fw2[n * 1024 + k] * hs[k];
#pragma unroll
        for (int off = 32; off; off >>= 1) p += __shfl_xor(p, off);
        if (lane == 0) h2[m * 32 + n] = fmaxf(p + fb2[n], 0.0f);
    }
}

// ---------------------------------------------------------------------------
// FC3 + theta construction. 128 threads = 32 batches x 4 outputs.
// ---------------------------------------------------------------------------
__global__ void fc3_theta_k(
    const float* __restrict__ h2, const float* __restrict__ fw3,
    const float* __restrict__ fb3, float* __restrict__ theta_out)
{
    int t = threadIdx.x;
    if (t >= 128) return;
    int m = t >> 2, j = t & 3;
    float s = fb3[j];
#pragma unroll
    for (int k = 0; k < 32; ++k) s += h2[m * 32 + k] * fw3[j * 32 + k];
    float* th = theta_out + m * 6;
    if (j == 0)      { th[0] = 1.0f / (1.0f + expf(-s)); th[1] = 0.0f; }
    else if (j == 1) { th[4] = 1.0f / (1.0f + expf(-s)); th[3] = 0.0f; }
    else if (j == 2) { th[2] = tanhf(s); }
    else             { th[5] = tanhf(s); }
}

// ---------------------------------------------------------------------------
// Bilinear grid-sample, padding_mode='zeros', align_corners=False. C=1.
// ---------------------------------------------------------------------------
__global__ __launch_bounds__(256) void sampler_k(
    const float* __restrict__ im, const float* __restrict__ theta,
    float* __restrict__ out)
{
    int idx = blockIdx.x * 256 + threadIdx.x;
    int x = idx & 255;
    int y = (idx >> 8) & 255;
    int b = idx >> 16;
    const float* th = theta + b * 6;
    float xsn = (2.0f * x + 1.0f) * (1.0f / 256.0f) - 1.0f;
    float ysn = (2.0f * y + 1.0f) * (1.0f / 256.0f) - 1.0f;
    float gx = th[0] * xsn + th[1] * ysn + th[2];
    float gy = th[3] * xsn + th[4] * ysn + th[5];
    float ix = ((gx + 1.0f) * 256.0f - 1.0f) * 0.5f;
    float iy = ((gy + 1.0f) * 256.0f - 1.0f) * 0.5f;
    float x0 = floorf(ix), y0 = floorf(iy);
    float wx1 = ix - x0, wy1 = iy - y0;
    float wx0 = 1.0f - wx1, wy0 = 1.0f - wy1;
    const float* src = im + (size_t)b * 65536;

    auto g = [&](float xf, float yf) -> float {
        if (xf < 0.0f || xf > 255.0f || yf < 0.0f || yf > 255.0f) return 0.0f;
        int xi = (int)xf, yi = (int)yf;
        return src[yi * 256 + xi];
    };
    float v00 = g(x0, y0);
    float v10 = g(x0 + 1.0f, y0);
    float v01 = g(x0, y0 + 1.0f);
    float v11 = g(x0 + 1.0f, y0 + 1.0f);
    out[idx] = v00 * wx0 * wy0 + v10 * wx1 * wy0 + v01 * wx0 * wy1 + v11 * wx1 * wy1;
}

// ---------------------------------------------------------------------------
// Workspace layout (floats), peak 15,466,496 floats = 61.9 MB:
//   x2   @ 0          (4,194,304)   32x8x128x128
//   x1c  @ 4,194,304  (8,388,608)   conv1 out, 16-batch chunk
//   x3   @ 4,194,304  (8,388,608)   32x16x128x128  (x1c dead after conv2)
//   x4   @ 12,582,912 (2,097,152)   32x16x64x64
//   x5   @ 4,194,304  (3,145,728)   32x24x64x64    (x3 dead after conv4)
//   x6   @ 14,680,064 (786,432)     32x24x32x32
//   part @ 0          (1,048,576)   split-K partials (x2 dead after conv4)
//   h1   @ 1,048,576  (32,768)
//   h2   @ 1,081,344  (1,024)
// ---------------------------------------------------------------------------
extern "C" void kernel_launch(void* const* d_in, const int* in_sizes, int n_in,
                              void* d_out, int out_size, void* d_ws, size_t ws_size,
                              hipStream_t stream)
{
    const float* im  = (const float*)d_in[0];
    const float* w1  = (const float*)d_in[1];  const float* b1 = (const float*)d_in[2];
    const float* w2  = (const float*)d_in[3];  const float* b2 = (const float*)d_in[4];
    const float* w3  = (const float*)d_in[5];  const float* b3 = (const float*)d_in[6];
    const float* w4  = (const float*)d_in[7];  const float* b4 = (const float*)d_in[8];
    const float* w5  = (const float*)d_in[9];  const float* b5 = (const float*)d_in[10];
    const float* w6  = (const float*)d_in[11]; const float* b6 = (const float*)d_in[12];
    const float* fw1 = (const float*)d_in[13]; const float* fb1 = (const float*)d_in[14];
    const float* fw2 = (const float*)d_in[15]; const float* fb2 = (const float*)d_in[16];
    const float* fw3 = (const float*)d_in[17]; const float* fb3 = (const float*)d_in[18];

    float* out = (float*)d_out;
    float* ws  = (float*)d_ws;

    float* x2   = ws + 0;
    float* x1c  = ws + 4194304;
    float* x3   = ws + 4194304;
    float* x4   = ws + 12582912;
    float* x5   = ws + 4194304;
    float* x6   = ws + 14680064;
    float* part = ws + 0;
    float* h1   = ws + 1048576;
    float* h2   = ws + 1081344;

    float* theta = out + 32 * 65536;

    // conv1 + conv2, chunked over batch (2 x 16) to bound workspace
    for (int c = 0; c < 2; ++c) {
        const float* imc = im + (size_t)c * 16 * 65536;
        convp_k<1, 0, 8, 1, 1><<<16 * 16 * 16, 256, 0, stream>>>(
            imc, nullptr, w1, b1, x1c, 256, 256);
        convp_k<8, 1, 8, 2, 9><<<16 * 8 * 8, 256, 0, stream>>>(
            x1c, imc, w2, b2, x2 + (size_t)c * 2097152, 256, 256);
    }
    convp_k<8, 0, 16, 1, 8><<<32 * 8 * 8, 256, 0, stream>>>(
        x2, nullptr, w3, b3, x3, 128, 128);
    convp_k<16, 8, 16, 2, 8><<<32 * 4 * 4, 256, 0, stream>>>(
        x3, x2, w4, b4, x4, 128, 128);
    convp_k<16, 0, 24, 1, 16><<<32 * 4 * 4, 256, 0, stream>>>(
        x4, nullptr, w5, b5, x5, 64, 64);
    convp_k<24, 16, 24, 2, 8><<<32 * 2 * 2, 256, 0, stream>>>(
        x5, x4, w6, b6, x6, 64, 64);

    // FC stack
    fc1_stage_k<<<dim3(16, FC1_KS), 256, 0, stream>>>(x6, fw1, part);
    fc1_reduce_k<<<128, 256, 0, stream>>>(part, fb1, h1);
    fc2_k<<<32, 256, 0, stream>>>(h1, fw2, fb2, h2);
    fc3_theta_k<<<1, 128, 0, stream>>>(h2, fw3, fb3, theta);

    // grid sample from theta (written into d_out tail, stream-ordered)
    sampler_k<<<8192, 256, 0, stream>>>(im, theta, out);
}

// Round 4
// 427.929 us; speedup vs baseline: 1.2607x; 1.2607x over previous
//
#include <hip/hip_runtime.h>
#include <hip/hip_bf16.h>

// ---------------------------------------------------------------------------
// LDS-staged direct 3x3 conv (pad=1), fused bias+ReLU, virtual concat of two
// inputs (CIN1 channels from in1, CIN2 from in2). Grid adds a cout-group dim:
// one block = one batch x one 16x16 output tile x CG output channels.
// One thread = one output pixel (identical math to the verified R3 kernel);
// per-block weight slice (CG*CIN*9*4 bytes <= 4.3KB) fits scalar L1.
// ---------------------------------------------------------------------------
template <int CIN1, int CIN2, int COUT, int CG, int STRIDE, int CCH>
__global__ __launch_bounds__(256) void convg_k(
    const float* __restrict__ in1, const float* __restrict__ in2,
    const float* __restrict__ w,    // [COUT][CIN1+CIN2][3][3]
    const float* __restrict__ bias, // [COUT]
    float* __restrict__ out,
    int Hin, int Win)
{
    constexpr int CIN = CIN1 + CIN2;
    constexpr int NG  = COUT / CG;   // cout groups
    constexpr int TO  = 16;
    constexpr int P   = TO * STRIDE + 2;
    constexpr int PX  = P + 1;
    __shared__ float Xs[CCH][P][PX];

    const int Ho = Hin / STRIDE, Wo = Win / STRIDE;
    const int tpr = Wo / TO, tpc = Ho / TO;
    int bid = blockIdx.x;
    const int tx = bid % tpr; bid /= tpr;
    const int ty = bid % tpc; bid /= tpc;
    const int g  = bid % NG;  bid /= NG;
    const int b  = bid;
    const int cbase = g * CG;

    const int tid = threadIdx.x;
    const int lx  = tid & 15;
    const int ly  = tid >> 4;

    const int y0 = ty * TO * STRIDE - 1;
    const int x0 = tx * TO * STRIDE - 1;
    const int HW = Hin * Win;

    float acc[CG];
#pragma unroll
    for (int co = 0; co < CG; ++co) acc[co] = bias[cbase + co];

    for (int cc = 0; cc < CIN; cc += CCH) {
        __syncthreads();
        // cooperative stage of CCH channels' (P x P) patch
        for (int c = 0; c < CCH; ++c) {
            int ci = cc + c;
            const float* src = (CIN2 == 0 || ci < CIN1)
                ? in1 + (size_t)(b * CIN1 + ci) * HW
                : in2 + (size_t)(b * CIN2 + (ci - CIN1)) * HW;
            for (int e = tid; e < P * P; e += 256) {
                int py = e / P, px = e % P;
                int gy = y0 + py, gx = x0 + px;
                bool ok = ((unsigned)gy < (unsigned)Hin) && ((unsigned)gx < (unsigned)Win);
                Xs[c][py][px] = ok ? src[gy * Win + gx] : 0.0f;
            }
        }
        __syncthreads();
        // compute: per channel, read 3x3 window once, FMA into CG couts
        for (int c = 0; c < CCH; ++c) {
            float win[9];
#pragma unroll
            for (int ky = 0; ky < 3; ++ky)
#pragma unroll
                for (int kx = 0; kx < 3; ++kx)
                    win[ky * 3 + kx] = Xs[c][ly * STRIDE + ky][lx * STRIDE + kx];
#pragma unroll
            for (int co = 0; co < CG; ++co) {
                const float* wp = w + ((size_t)(cbase + co) * CIN + cc + c) * 9;
#pragma unroll
                for (int k = 0; k < 9; ++k)
                    acc[co] += win[k] * wp[k];
            }
        }
    }

    const int oy = ty * TO + ly;
    const int ox = tx * TO + lx;
#pragma unroll
    for (int co = 0; co < CG; ++co)
        out[((size_t)(b * COUT + cbase + co) * Ho + oy) * Wo + ox] = fmaxf(acc[co], 0.0f);
}

// ---------------------------------------------------------------------------
// FC1: h[32,1024] = relu(xs[32,24576] @ fw1[1024,24576]^T + fb1)
// (verified: split-K 32 chunks of 768, 64-n tile per block)
// ---------------------------------------------------------------------------
#define FC1_K 24576
#define FC1_N 1024
#define FC1_M 32
#define FC1_KS 32   // k splits
#define FC1_KC 768  // k per split
#define FC1_KP 64   // k per phase
#define FC1_NT 64   // n per block

__global__ __launch_bounds__(256) void fc1_stage_k(
    const float* __restrict__ xs,   // [32][24576]
    const float* __restrict__ fw1,  // [1024][24576]
    float* __restrict__ part)       // [KS][32][1024]
{
    __shared__ __align__(16) float As[FC1_KP][36];
    __shared__ __align__(16) float Bs[FC1_KP][66];

    const int tid = threadIdx.x;
    const int n0 = blockIdx.x * FC1_NT;
    const int ks = blockIdx.y;
    const int k0 = ks * FC1_KC;
    const int lane = tid & 63;
    const int grp = tid >> 6;

    const int m4 = (tid & 7) * 4;
    const int n2 = (tid >> 3) * 2;

    float acc[4][2];
#pragma unroll
    for (int i = 0; i < 4; ++i)
#pragma unroll
        for (int j = 0; j < 2; ++j) acc[i][j] = 0.0f;

    for (int p = 0; p < FC1_KC / FC1_KP; ++p) {
        const int kc = k0 + p * FC1_KP;
#pragma unroll
        for (int r = 0; r < 8; ++r) {
            int m = grp * 8 + r;
            As[lane][m] = xs[(size_t)m * FC1_K + kc + lane];
        }
#pragma unroll
        for (int r = 0; r < 16; ++r) {
            int nl = grp * 16 + r;
            Bs[lane][nl] = fw1[(size_t)(n0 + nl) * FC1_K + kc + lane];
        }
        __syncthreads();
#pragma unroll 8
        for (int k = 0; k < FC1_KP; ++k) {
            float4 a = *(const float4*)&As[k][m4];
            float2 bv = *(const float2*)&Bs[k][n2];
            acc[0][0] += a.x * bv.x; acc[0][1] += a.x * bv.y;
            acc[1][0] += a.y * bv.x; acc[1][1] += a.y * bv.y;
            acc[2][0] += a.z * bv.x; acc[2][1] += a.z * bv.y;
            acc[3][0] += a.w * bv.x; acc[3][1] += a.w * bv.y;
        }
        __syncthreads();
    }
#pragma unroll
    for (int i = 0; i < 4; ++i)
#pragma unroll
        for (int j = 0; j < 2; ++j)
            part[((size_t)ks * FC1_M + (m4 + i)) * FC1_N + n0 + n2 + j] = acc[i][j];
}

__global__ __launch_bounds__(256) void fc1_reduce_k(
    const float* __restrict__ part, const float* __restrict__ fb1,
    float* __restrict__ h1)
{
    int idx = blockIdx.x * 256 + threadIdx.x; // 32768
    int n = idx & (FC1_N - 1);
    int m = idx >> 10;
    float s = fb1[n];
#pragma unroll
    for (int ks = 0; ks < FC1_KS; ++ks)
        s += part[((size_t)ks * FC1_M + m) * FC1_N + n];
    h1[idx] = fmaxf(s, 0.0f);
}

// ---------------------------------------------------------------------------
// FC2: h2[32,32] = relu(h1[32,1024] @ fw2[32,1024]^T + fb2). One block per m.
// ---------------------------------------------------------------------------
__global__ __launch_bounds__(256) void fc2_k(
    const float* __restrict__ h1, const float* __restrict__ fw2,
    const float* __restrict__ fb2, float* __restrict__ h2)
{
    __shared__ float hs[1024];
    const int m = blockIdx.x;
    const int tid = threadIdx.x;
    for (int i = tid; i < 1024; i += 256) hs[i] = h1[m * 1024 + i];
    __syncthreads();
    const int wave = tid >> 6, lane = tid & 63;
#pragma unroll 1
    for (int nn = 0; nn < 8; ++nn) {
        int n = wave * 8 + nn;
        float p = 0.0f;
        for (int k = lane; k < 1024; k += 64)
            p += fw2[n * 1024 + k] * hs[k];
#pragma unroll
        for (int off = 32; off; off >>= 1) p += __shfl_xor(p, off);
        if (lane == 0) h2[m * 32 + n] = fmaxf(p + fb2[n], 0.0f);
    }
}

// ---------------------------------------------------------------------------
// FC3 + theta construction. 128 threads = 32 batches x 4 outputs.
// ---------------------------------------------------------------------------
__global__ void fc3_theta_k(
    const float* __restrict__ h2, const float* __restrict__ fw3,
    const float* __restrict__ fb3, float* __restrict__ theta_out)
{
    int t = threadIdx.x;
    if (t >= 128) return;
    int m = t >> 2, j = t & 3;
    float s = fb3[j];
#pragma unroll
    for (int k = 0; k < 32; ++k) s += h2[m * 32 + k] * fw3[j * 32 + k];
    float* th = theta_out + m * 6;
    if (j == 0)      { th[0] = 1.0f / (1.0f + expf(-s)); th[1] = 0.0f; }
    else if (j == 1) { th[4] = 1.0f / (1.0f + expf(-s)); th[3] = 0.0f; }
    else if (j == 2) { th[2] = tanhf(s); }
    else             { th[5] = tanhf(s); }
}

// ---------------------------------------------------------------------------
// Bilinear grid-sample, padding_mode='zeros', align_corners=False. C=1.
// ---------------------------------------------------------------------------
__global__ __launch_bounds__(256) void sampler_k(
    const float* __restrict__ im, const float* __restrict__ theta,
    float* __restrict__ out)
{
    int idx = blockIdx.x * 256 + threadIdx.x;
    int x = idx & 255;
    int y = (idx >> 8) & 255;
    int b = idx >> 16;
    const float* th = theta + b * 6;
    float xsn = (2.0f * x + 1.0f) * (1.0f / 256.0f) - 1.0f;
    float ysn = (2.0f * y + 1.0f) * (1.0f / 256.0f) - 1.0f;
    float gx = th[0] * xsn + th[1] * ysn + th[2];
    float gy = th[3] * xsn + th[4] * ysn + th[5];
    float ix = ((gx + 1.0f) * 256.0f - 1.0f) * 0.5f;
    float iy = ((gy + 1.0f) * 256.0f - 1.0f) * 0.5f;
    float x0 = floorf(ix), y0 = floorf(iy);
    float wx1 = ix - x0, wy1 = iy - y0;
    float wx0 = 1.0f - wx1, wy0 = 1.0f - wy1;
    const float* src = im + (size_t)b * 65536;

    auto g = [&](float xf, float yf) -> float {
        if (xf < 0.0f || xf > 255.0f || yf < 0.0f || yf > 255.0f) return 0.0f;
        int xi = (int)xf, yi = (int)yf;
        return src[yi * 256 + xi];
    };
    float v00 = g(x0, y0);
    float v10 = g(x0 + 1.0f, y0);
    float v01 = g(x0, y0 + 1.0f);
    float v11 = g(x0 + 1.0f, y0 + 1.0f);
    out[idx] = v00 * wx0 * wy0 + v10 * wx1 * wy0 + v01 * wx0 * wy1 + v11 * wx1 * wy1;
}

// ---------------------------------------------------------------------------
// Workspace layout (floats), peak 15,466,496 floats = 61.9 MB (as R3, proven):
//   x2   @ 0          (4,194,304)   32x8x128x128
//   x1c  @ 4,194,304  (8,388,608)   conv1 out, 16-batch chunk
//   x3   @ 4,194,304  (8,388,608)   32x16x128x128  (x1c dead after conv2)
//   x4   @ 12,582,912 (2,097,152)   32x16x64x64
//   x5   @ 4,194,304  (3,145,728)   32x24x64x64    (x3 dead after conv4)
//   x6   @ 14,680,064 (786,432)     32x24x32x32
//   part @ 0          (1,048,576)   split-K partials (x2 dead after conv4)
//   h1   @ 1,048,576  (32,768)
//   h2   @ 1,081,344  (1,024)
// ---------------------------------------------------------------------------
extern "C" void kernel_launch(void* const* d_in, const int* in_sizes, int n_in,
                              void* d_out, int out_size, void* d_ws, size_t ws_size,
                              hipStream_t stream)
{
    const float* im  = (const float*)d_in[0];
    const float* w1  = (const float*)d_in[1];  const float* b1 = (const float*)d_in[2];
    const float* w2  = (const float*)d_in[3];  const float* b2 = (const float*)d_in[4];
    const float* w3  = (const float*)d_in[5];  const float* b3 = (const float*)d_in[6];
    const float* w4  = (const float*)d_in[7];  const float* b4 = (const float*)d_in[8];
    const float* w5  = (const float*)d_in[9];  const float* b5 = (const float*)d_in[10];
    const float* w6  = (const float*)d_in[11]; const float* b6 = (const float*)d_in[12];
    const float* fw1 = (const float*)d_in[13]; const float* fb1 = (const float*)d_in[14];
    const float* fw2 = (const float*)d_in[15]; const float* fb2 = (const float*)d_in[16];
    const float* fw3 = (const float*)d_in[17]; const float* fb3 = (const float*)d_in[18];

    float* out = (float*)d_out;
    float* ws  = (float*)d_ws;

    float* x2   = ws + 0;
    float* x1c  = ws + 4194304;
    float* x3   = ws + 4194304;
    float* x4   = ws + 12582912;
    float* x5   = ws + 4194304;
    float* x6   = ws + 14680064;
    float* part = ws + 0;
    float* h1   = ws + 1048576;
    float* h2   = ws + 1081344;

    float* theta = out + 32 * 65536;

    // conv1 + conv2, chunked over batch (2 x 16) to bound workspace
    for (int c = 0; c < 2; ++c) {
        const float* imc = im + (size_t)c * 16 * 65536;
        // grid = B*tpc*tpr*NG
        convg_k<1, 0, 8, 8, 1, 1><<<16 * 16 * 16, 256, 0, stream>>>(
            imc, nullptr, w1, b1, x1c, 256, 256);
        convg_k<8, 1, 8, 8, 2, 3><<<16 * 8 * 8, 256, 0, stream>>>(
            x1c, imc, w2, b2, x2 + (size_t)c * 2097152, 256, 256);
    }
    convg_k<8, 0, 16, 8, 1, 8><<<32 * 8 * 8 * 2, 256, 0, stream>>>(
        x2, nullptr, w3, b3, x3, 128, 128);
    convg_k<16, 8, 16, 4, 2, 4><<<32 * 4 * 4 * 4, 256, 0, stream>>>(
        x3, x2, w4, b4, x4, 128, 128);
    convg_k<16, 0, 24, 6, 1, 8><<<32 * 4 * 4 * 4, 256, 0, stream>>>(
        x4, nullptr, w5, b5, x5, 64, 64);
    convg_k<24, 16, 24, 3, 2, 8><<<32 * 2 * 2 * 8, 256, 0, stream>>>(
        x5, x4, w6, b6, x6, 64, 64);

    // FC stack
    fc1_stage_k<<<dim3(16, FC1_KS), 256, 0, stream>>>(x6, fw1, part);
    fc1_reduce_k<<<128, 256, 0, stream>>>(part, fb1, h1);
    fc2_k<<<32, 256, 0, stream>>>(h1, fw2, fb2, h2);
    fc3_theta_k<<<1, 128, 0, stream>>>(h2, fw3, fb3, theta);

    // grid sample from theta (written into d_out tail, stream-ordered)
    sampler_k<<<8192, 256, 0, stream>>>(im, theta, out);
}

// Round 5
// 358.759 us; speedup vs baseline: 1.5038x; 1.1928x over previous
//
#include <hip/hip_runtime.h>
#include <hip/hip_bf16.h>

// ---------------------------------------------------------------------------
// LDS-staged direct 3x3 conv (pad=1), fused bias+ReLU, virtual concat of two
// inputs (CIN1 from in1, CIN2 from in2). One block = one batch x one 16x16
// output tile x CG output channels; one thread = one output pixel (index math
// identical to the twice-verified kernel). NEW: double-buffered LDS with
// register-staged prefetch — next chunk's global loads are issued before
// computing the current chunk, committed to the other LDS buffer after.
// One barrier per chunk.
// ---------------------------------------------------------------------------
template <int CIN1, int CIN2, int COUT, int CG, int STRIDE, int CCH>
__global__ __launch_bounds__(256) void convg_k(
    const float* __restrict__ in1, const float* __restrict__ in2,
    const float* __restrict__ w,    // [COUT][CIN1+CIN2][3][3]
    const float* __restrict__ bias, // [COUT]
    float* __restrict__ out,
    int Hin, int Win)
{
    constexpr int CIN = CIN1 + CIN2;
    constexpr int NG  = COUT / CG;       // cout groups
    constexpr int NCH = CIN / CCH;       // channel chunks
    constexpr int TO  = 16;
    constexpr int P   = TO * STRIDE + 2;
    constexpr int PX  = P + 1;
    constexpr int NLD = (CCH * P * P + 255) / 256;  // reg-staged loads/chunk
    __shared__ float Xs[2][CCH][P][PX];

    const int Ho = Hin / STRIDE, Wo = Win / STRIDE;
    const int tpr = Wo / TO, tpc = Ho / TO;
    int bid = blockIdx.x;
    const int tx = bid % tpr; bid /= tpr;
    const int ty = bid % tpc; bid /= tpc;
    const int g  = bid % NG;  bid /= NG;
    const int b  = bid;
    const int cbase = g * CG;

    const int tid = threadIdx.x;
    const int lx  = tid & 15;
    const int ly  = tid >> 4;

    const int y0 = ty * TO * STRIDE - 1;
    const int x0 = tx * TO * STRIDE - 1;
    const int HW = Hin * Win;

    float acc[CG];
#pragma unroll
    for (int co = 0; co < CG; ++co) acc[co] = bias[cbase + co];

    float stg[NLD];

    // issue chunk cc's global loads into stg[] (no LDS writes)
    auto issue = [&](int cc) {
#pragma unroll
        for (int l = 0; l < NLD; ++l) {
            int e = tid + l * 256;
            float v = 0.0f;
            if (e < CCH * P * P) {
                int c = e / (P * P), r = e % (P * P);
                int py = r / P, px = r % P;
                int ci = cc + c;
                const float* src = (CIN2 == 0 || ci < CIN1)
                    ? in1 + (size_t)(b * CIN1 + ci) * HW
                    : in2 + (size_t)(b * CIN2 + (ci - CIN1)) * HW;
                int gy = y0 + py, gx = x0 + px;
                bool ok = ((unsigned)gy < (unsigned)Hin) && ((unsigned)gx < (unsigned)Win);
                if (ok) v = src[gy * Win + gx];
            }
            stg[l] = v;
        }
    };
    // commit stg[] to LDS buffer `buf`
    auto commit = [&](int bf) {
        float* dst = &Xs[bf][0][0][0];
#pragma unroll
        for (int l = 0; l < NLD; ++l) {
            int e = tid + l * 256;
            if (e < CCH * P * P) {
                int c = e / (P * P), r = e % (P * P);
                dst[c * (P * PX) + (r / P) * PX + (r % P)] = stg[l];
            }
        }
    };

    issue(0);
    commit(0);
    __syncthreads();

    int buf = 0;
    for (int ch = 0; ch < NCH; ++ch) {
        if (ch + 1 < NCH) issue((ch + 1) * CCH);   // loads in flight
        // compute chunk ch from Xs[buf]
        for (int c = 0; c < CCH; ++c) {
            float win[9];
#pragma unroll
            for (int ky = 0; ky < 3; ++ky)
#pragma unroll
                for (int kx = 0; kx < 3; ++kx)
                    win[ky * 3 + kx] = Xs[buf][c][ly * STRIDE + ky][lx * STRIDE + kx];
#pragma unroll
            for (int co = 0; co < CG; ++co) {
                const float* wp = w + ((size_t)(cbase + co) * CIN + ch * CCH + c) * 9;
#pragma unroll
                for (int k = 0; k < 9; ++k)
                    acc[co] += win[k] * wp[k];
            }
        }
        if (ch + 1 < NCH) {
            commit(buf ^ 1);       // vmcnt wait lands here, after compute
            __syncthreads();
            buf ^= 1;
        }
    }

    const int oy = ty * TO + ly;
    const int ox = tx * TO + lx;
#pragma unroll
    for (int co = 0; co < CG; ++co)
        out[((size_t)(b * COUT + cbase + co) * Ho + oy) * Wo + ox] = fmaxf(acc[co], 0.0f);
}

// ---------------------------------------------------------------------------
// FC1: h[32,1024] = relu(xs[32,24576] @ fw1[1024,24576]^T + fb1)
// (verified: split-K 32 chunks of 768, 64-n tile per block)
// ---------------------------------------------------------------------------
#define FC1_K 24576
#define FC1_N 1024
#define FC1_M 32
#define FC1_KS 32   // k splits
#define FC1_KC 768  // k per split
#define FC1_KP 64   // k per phase
#define FC1_NT 64   // n per block

__global__ __launch_bounds__(256) void fc1_stage_k(
    const float* __restrict__ xs,   // [32][24576]
    const float* __restrict__ fw1,  // [1024][24576]
    float* __restrict__ part)       // [KS][32][1024]
{
    __shared__ __align__(16) float As[FC1_KP][36];
    __shared__ __align__(16) float Bs[FC1_KP][66];

    const int tid = threadIdx.x;
    const int n0 = blockIdx.x * FC1_NT;
    const int ks = blockIdx.y;
    const int k0 = ks * FC1_KC;
    const int lane = tid & 63;
    const int grp = tid >> 6;

    const int m4 = (tid & 7) * 4;
    const int n2 = (tid >> 3) * 2;

    float acc[4][2];
#pragma unroll
    for (int i = 0; i < 4; ++i)
#pragma unroll
        for (int j = 0; j < 2; ++j) acc[i][j] = 0.0f;

    for (int p = 0; p < FC1_KC / FC1_KP; ++p) {
        const int kc = k0 + p * FC1_KP;
#pragma unroll
        for (int r = 0; r < 8; ++r) {
            int m = grp * 8 + r;
            As[lane][m] = xs[(size_t)m * FC1_K + kc + lane];
        }
#pragma unroll
        for (int r = 0; r < 16; ++r) {
            int nl = grp * 16 + r;
            Bs[lane][nl] = fw1[(size_t)(n0 + nl) * FC1_K + kc + lane];
        }
        __syncthreads();
#pragma unroll 8
        for (int k = 0; k < FC1_KP; ++k) {
            float4 a = *(const float4*)&As[k][m4];
            float2 bv = *(const float2*)&Bs[k][n2];
            acc[0][0] += a.x * bv.x; acc[0][1] += a.x * bv.y;
            acc[1][0] += a.y * bv.x; acc[1][1] += a.y * bv.y;
            acc[2][0] += a.z * bv.x; acc[2][1] += a.z * bv.y;
            acc[3][0] += a.w * bv.x; acc[3][1] += a.w * bv.y;
        }
        __syncthreads();
    }
#pragma unroll
    for (int i = 0; i < 4; ++i)
#pragma unroll
        for (int j = 0; j < 2; ++j)
            part[((size_t)ks * FC1_M + (m4 + i)) * FC1_N + n0 + n2 + j] = acc[i][j];
}

__global__ __launch_bounds__(256) void fc1_reduce_k(
    const float* __restrict__ part, const float* __restrict__ fb1,
    float* __restrict__ h1)
{
    int idx = blockIdx.x * 256 + threadIdx.x; // 32768
    int n = idx & (FC1_N - 1);
    int m = idx >> 10;
    float s = fb1[n];
#pragma unroll
    for (int ks = 0; ks < FC1_KS; ++ks)
        s += part[((size_t)ks * FC1_M + m) * FC1_N + n];
    h1[idx] = fmaxf(s, 0.0f);
}

// ---------------------------------------------------------------------------
// FC2: h2[32,32] = relu(h1[32,1024] @ fw2[32,1024]^T + fb2). One block per m.
// ---------------------------------------------------------------------------
__global__ __launch_bounds__(256) void fc2_k(
    const float* __restrict__ h1, const float* __restrict__ fw2,
    const float* __restrict__ fb2, float* __restrict__ h2)
{
    __shared__ float hs[1024];
    const int m = blockIdx.x;
    const int tid = threadIdx.x;
    for (int i = tid; i < 1024; i += 256) hs[i] = h1[m * 1024 + i];
    __syncthreads();
    const int wave = tid >> 6, lane = tid & 63;
#pragma unroll 1
    for (int nn = 0; nn < 8; ++nn) {
        int n = wave * 8 + nn;
        float p = 0.0f;
        for (int k = lane; k < 1024; k += 64)
            p += fw2[n * 1024 + k] * hs[k];
#pragma unroll
        for (int off = 32; off; off >>= 1) p += __shfl_xor(p, off);
        if (lane == 0) h2[m * 32 + n] = fmaxf(p + fb2[n], 0.0f);
    }
}

// ---------------------------------------------------------------------------
// FC3 + theta construction. 128 threads = 32 batches x 4 outputs.
// ---------------------------------------------------------------------------
__global__ void fc3_theta_k(
    const float* __restrict__ h2, const float* __restrict__ fw3,
    const float* __restrict__ fb3, float* __restrict__ theta_out)
{
    int t = threadIdx.x;
    if (t >= 128) return;
    int m = t >> 2, j = t & 3;
    float s = fb3[j];
#pragma unroll
    for (int k = 0; k < 32; ++k) s += h2[m * 32 + k] * fw3[j * 32 + k];
    float* th = theta_out + m * 6;
    if (j == 0)      { th[0] = 1.0f / (1.0f + expf(-s)); th[1] = 0.0f; }
    else if (j == 1) { th[4] = 1.0f / (1.0f + expf(-s)); th[3] = 0.0f; }
    else if (j == 2) { th[2] = tanhf(s); }
    else             { th[5] = tanhf(s); }
}

// ---------------------------------------------------------------------------
// Bilinear grid-sample, padding_mode='zeros', align_corners=False. C=1.
// ---------------------------------------------------------------------------
__global__ __launch_bounds__(256) void sampler_k(
    const float* __restrict__ im, const float* __restrict__ theta,
    float* __restrict__ out)
{
    int idx = blockIdx.x * 256 + threadIdx.x;
    int x = idx & 255;
    int y = (idx >> 8) & 255;
    int b = idx >> 16;
    const float* th = theta + b * 6;
    float xsn = (2.0f * x + 1.0f) * (1.0f / 256.0f) - 1.0f;
    float ysn = (2.0f * y + 1.0f) * (1.0f / 256.0f) - 1.0f;
    float gx = th[0] * xsn + th[1] * ysn + th[2];
    float gy = th[3] * xsn + th[4] * ysn + th[5];
    float ix = ((gx + 1.0f) * 256.0f - 1.0f) * 0.5f;
    float iy = ((gy + 1.0f) * 256.0f - 1.0f) * 0.5f;
    float x0 = floorf(ix), y0 = floorf(iy);
    float wx1 = ix - x0, wy1 = iy - y0;
    float wx0 = 1.0f - wx1, wy0 = 1.0f - wy1;
    const float* src = im + (size_t)b * 65536;

    auto g = [&](float xf, float yf) -> float {
        if (xf < 0.0f || xf > 255.0f || yf < 0.0f || yf > 255.0f) return 0.0f;
        int xi = (int)xf, yi = (int)yf;
        return src[yi * 256 + xi];
    };
    float v00 = g(x0, y0);
    float v10 = g(x0 + 1.0f, y0);
    float v01 = g(x0, y0 + 1.0f);
    float v11 = g(x0 + 1.0f, y0 + 1.0f);
    out[idx] = v00 * wx0 * wy0 + v10 * wx1 * wy0 + v01 * wx0 * wy1 + v11 * wx1 * wy1;
}

// ---------------------------------------------------------------------------
// Workspace layout (floats), peak 15,466,496 floats = 61.9 MB (verified):
//   x2   @ 0          (4,194,304)   32x8x128x128
//   x1c  @ 4,194,304  (8,388,608)   conv1 out, 16-batch chunk
//   x3   @ 4,194,304  (8,388,608)   32x16x128x128  (x1c dead after conv2)
//   x4   @ 12,582,912 (2,097,152)   32x16x64x64
//   x5   @ 4,194,304  (3,145,728)   32x24x64x64    (x3 dead after conv4)
//   x6   @ 14,680,064 (786,432)     32x24x32x32
//   part @ 0          (1,048,576)   split-K partials (x2 dead after conv4)
//   h1   @ 1,048,576  (32,768)
//   h2   @ 1,081,344  (1,024)
// ---------------------------------------------------------------------------
extern "C" void kernel_launch(void* const* d_in, const int* in_sizes, int n_in,
                              void* d_out, int out_size, void* d_ws, size_t ws_size,
                              hipStream_t stream)
{
    const float* im  = (const float*)d_in[0];
    const float* w1  = (const float*)d_in[1];  const float* b1 = (const float*)d_in[2];
    const float* w2  = (const float*)d_in[3];  const float* b2 = (const float*)d_in[4];
    const float* w3  = (const float*)d_in[5];  const float* b3 = (const float*)d_in[6];
    const float* w4  = (const float*)d_in[7];  const float* b4 = (const float*)d_in[8];
    const float* w5  = (const float*)d_in[9];  const float* b5 = (const float*)d_in[10];
    const float* w6  = (const float*)d_in[11]; const float* b6 = (const float*)d_in[12];
    const float* fw1 = (const float*)d_in[13]; const float* fb1 = (const float*)d_in[14];
    const float* fw2 = (const float*)d_in[15]; const float* fb2 = (const float*)d_in[16];
    const float* fw3 = (const float*)d_in[17]; const float* fb3 = (const float*)d_in[18];

    float* out = (float*)d_out;
    float* ws  = (float*)d_ws;

    float* x2   = ws + 0;
    float* x1c  = ws + 4194304;
    float* x3   = ws + 4194304;
    float* x4   = ws + 12582912;
    float* x5   = ws + 4194304;
    float* x6   = ws + 14680064;
    float* part = ws + 0;
    float* h1   = ws + 1048576;
    float* h2   = ws + 1081344;

    float* theta = out + 32 * 65536;

    // conv1 + conv2, chunked over batch (2 x 16) to bound workspace
    for (int c = 0; c < 2; ++c) {
        const float* imc = im + (size_t)c * 16 * 65536;
        // <CIN1,CIN2,COUT,CG,STRIDE,CCH>  grid = B*tpc*tpr*NG
        convg_k<1, 0, 8, 8, 1, 1><<<16 * 16 * 16, 256, 0, stream>>>(
            imc, nullptr, w1, b1, x1c, 256, 256);
        convg_k<8, 1, 8, 8, 2, 1><<<16 * 8 * 8, 256, 0, stream>>>(
            x1c, imc, w2, b2, x2 + (size_t)c * 2097152, 256, 256);
    }
    convg_k<8, 0, 16, 16, 1, 2><<<32 * 8 * 8, 256, 0, stream>>>(
        x2, nullptr, w3, b3, x3, 128, 128);
    convg_k<16, 8, 16, 8, 2, 2><<<32 * 4 * 4 * 2, 256, 0, stream>>>(
        x3, x2, w4, b4, x4, 128, 128);
    convg_k<16, 0, 24, 12, 1, 2><<<32 * 4 * 4 * 2, 256, 0, stream>>>(
        x4, nullptr, w5, b5, x5, 64, 64);
    convg_k<24, 16, 24, 6, 2, 2><<<32 * 2 * 2 * 4, 256, 0, stream>>>(
        x5, x4, w6, b6, x6, 64, 64);

    // FC stack
    fc1_stage_k<<<dim3(16, FC1_KS), 256, 0, stream>>>(x6, fw1, part);
    fc1_reduce_k<<<128, 256, 0, stream>>>(part, fb1, h1);
    fc2_k<<<32, 256, 0, stream>>>(h1, fw2, fb2, h2);
    fc3_theta_k<<<1, 128, 0, stream>>>(h2, fw3, fb3, theta);

    // grid sample from theta (written into d_out tail, stream-ordered)
    sampler_k<<<8192, 256, 0, stream>>>(im, theta, out);
}

// Round 6
// 338.335 us; speedup vs baseline: 1.5946x; 1.0604x over previous
//
#include <hip/hip_runtime.h>
#include <hip/hip_bf16.h>

// ---------------------------------------------------------------------------
// LDS-staged direct 3x3 conv (pad=1), fused bias+ReLU, virtual concat of two
// inputs (CIN1 from in1, CIN2 from in2). One block = one batch x one 16x16
// output tile x CG output channels; one thread = one output pixel (index math
// identical to the verified kernel). Double-buffered LDS with register-staged
// prefetch; one barrier per chunk. __launch_bounds__(256,8) pins VGPR <= 64
// (occupancy cliff per m69: waves/CU halve at vgpr=64).
// ---------------------------------------------------------------------------
template <int CIN1, int CIN2, int COUT, int CG, int STRIDE, int CCH>
__global__ __launch_bounds__(256, 8) void convg_k(
    const float* __restrict__ in1, const float* __restrict__ in2,
    const float* __restrict__ w,    // [COUT][CIN1+CIN2][3][3]
    const float* __restrict__ bias, // [COUT]
    float* __restrict__ out,
    int Hin, int Win)
{
    constexpr int CIN = CIN1 + CIN2;
    constexpr int NG  = COUT / CG;       // cout groups
    constexpr int NCH = CIN / CCH;       // channel chunks
    constexpr int TO  = 16;
    constexpr int P   = TO * STRIDE + 2;
    constexpr int PX  = P + 1;
    constexpr int NLD = (CCH * P * P + 255) / 256;  // reg-staged loads/chunk
    __shared__ float Xs[2][CCH][P][PX];

    const int Ho = Hin / STRIDE, Wo = Win / STRIDE;
    const int tpr = Wo / TO, tpc = Ho / TO;
    int bid = blockIdx.x;
    const int tx = bid % tpr; bid /= tpr;
    const int ty = bid % tpc; bid /= tpc;
    const int g  = bid % NG;  bid /= NG;
    const int b  = bid;
    const int cbase = g * CG;

    const int tid = threadIdx.x;
    const int lx  = tid & 15;
    const int ly  = tid >> 4;

    const int y0 = ty * TO * STRIDE - 1;
    const int x0 = tx * TO * STRIDE - 1;
    const int HW = Hin * Win;

    float acc[CG];
#pragma unroll
    for (int co = 0; co < CG; ++co) acc[co] = bias[cbase + co];

    float stg[NLD];

    // issue chunk cc's global loads into stg[] (no LDS writes)
    auto issue = [&](int cc) {
#pragma unroll
        for (int l = 0; l < NLD; ++l) {
            int e = tid + l * 256;
            float v = 0.0f;
            if (e < CCH * P * P) {
                int c = e / (P * P), r = e % (P * P);
                int py = r / P, px = r % P;
                int ci = cc + c;
                const float* src = (CIN2 == 0 || ci < CIN1)
                    ? in1 + (size_t)(b * CIN1 + ci) * HW
                    : in2 + (size_t)(b * CIN2 + (ci - CIN1)) * HW;
                int gy = y0 + py, gx = x0 + px;
                bool ok = ((unsigned)gy < (unsigned)Hin) && ((unsigned)gx < (unsigned)Win);
                if (ok) v = src[gy * Win + gx];
            }
            stg[l] = v;
        }
    };
    // commit stg[] to LDS buffer `buf`
    auto commit = [&](int bf) {
        float* dst = &Xs[bf][0][0][0];
#pragma unroll
        for (int l = 0; l < NLD; ++l) {
            int e = tid + l * 256;
            if (e < CCH * P * P) {
                int c = e / (P * P), r = e % (P * P);
                dst[c * (P * PX) + (r / P) * PX + (r % P)] = stg[l];
            }
        }
    };

    issue(0);
    commit(0);
    __syncthreads();

    int buf = 0;
    for (int ch = 0; ch < NCH; ++ch) {
        if (ch + 1 < NCH) issue((ch + 1) * CCH);   // loads in flight
        // compute chunk ch from Xs[buf]
        for (int c = 0; c < CCH; ++c) {
            float win[9];
#pragma unroll
            for (int ky = 0; ky < 3; ++ky)
#pragma unroll
                for (int kx = 0; kx < 3; ++kx)
                    win[ky * 3 + kx] = Xs[buf][c][ly * STRIDE + ky][lx * STRIDE + kx];
#pragma unroll
            for (int co = 0; co < CG; ++co) {
                const float* wp = w + ((size_t)(cbase + co) * CIN + ch * CCH + c) * 9;
#pragma unroll
                for (int k = 0; k < 9; ++k)
                    acc[co] += win[k] * wp[k];
            }
        }
        if (ch + 1 < NCH) {
            commit(buf ^ 1);       // vmcnt wait lands here, after compute
            __syncthreads();
            buf ^= 1;
        }
    }

    const int oy = ty * TO + ly;
    const int ox = tx * TO + lx;
#pragma unroll
    for (int co = 0; co < CG; ++co)
        out[((size_t)(b * COUT + cbase + co) * Ho + oy) * Wo + ox] = fmaxf(acc[co], 0.0f);
}

// ---------------------------------------------------------------------------
// FC1: h[32,1024] = relu(xs[32,24576] @ fw1[1024,24576]^T + fb1)
// (verified: split-K 32 chunks of 768, 64-n tile per block)
// ---------------------------------------------------------------------------
#define FC1_K 24576
#define FC1_N 1024
#define FC1_M 32
#define FC1_KS 32   // k splits
#define FC1_KC 768  // k per split
#define FC1_KP 64   // k per phase
#define FC1_NT 64   // n per block

__global__ __launch_bounds__(256) void fc1_stage_k(
    const float* __restrict__ xs,   // [32][24576]
    const float* __restrict__ fw1,  // [1024][24576]
    float* __restrict__ part)       // [KS][32][1024]
{
    __shared__ __align__(16) float As[FC1_KP][36];
    __shared__ __align__(16) float Bs[FC1_KP][66];

    const int tid = threadIdx.x;
    const int n0 = blockIdx.x * FC1_NT;
    const int ks = blockIdx.y;
    const int k0 = ks * FC1_KC;
    const int lane = tid & 63;
    const int grp = tid >> 6;

    const int m4 = (tid & 7) * 4;
    const int n2 = (tid >> 3) * 2;

    float acc[4][2];
#pragma unroll
    for (int i = 0; i < 4; ++i)
#pragma unroll
        for (int j = 0; j < 2; ++j) acc[i][j] = 0.0f;

    for (int p = 0; p < FC1_KC / FC1_KP; ++p) {
        const int kc = k0 + p * FC1_KP;
#pragma unroll
        for (int r = 0; r < 8; ++r) {
            int m = grp * 8 + r;
            As[lane][m] = xs[(size_t)m * FC1_K + kc + lane];
        }
#pragma unroll
        for (int r = 0; r < 16; ++r) {
            int nl = grp * 16 + r;
            Bs[lane][nl] = fw1[(size_t)(n0 + nl) * FC1_K + kc + lane];
        }
        __syncthreads();
#pragma unroll 8
        for (int k = 0; k < FC1_KP; ++k) {
            float4 a = *(const float4*)&As[k][m4];
            float2 bv = *(const float2*)&Bs[k][n2];
            acc[0][0] += a.x * bv.x; acc[0][1] += a.x * bv.y;
            acc[1][0] += a.y * bv.x; acc[1][1] += a.y * bv.y;
            acc[2][0] += a.z * bv.x; acc[2][1] += a.z * bv.y;
            acc[3][0] += a.w * bv.x; acc[3][1] += a.w * bv.y;
        }
        __syncthreads();
    }
#pragma unroll
    for (int i = 0; i < 4; ++i)
#pragma unroll
        for (int j = 0; j < 2; ++j)
            part[((size_t)ks * FC1_M + (m4 + i)) * FC1_N + n0 + n2 + j] = acc[i][j];
}

__global__ __launch_bounds__(256) void fc1_reduce_k(
    const float* __restrict__ part, const float* __restrict__ fb1,
    float* __restrict__ h1)
{
    int idx = blockIdx.x * 256 + threadIdx.x; // 32768
    int n = idx & (FC1_N - 1);
    int m = idx >> 10;
    float s = fb1[n];
#pragma unroll
    for (int ks = 0; ks < FC1_KS; ++ks)
        s += part[((size_t)ks * FC1_M + m) * FC1_N + n];
    h1[idx] = fmaxf(s, 0.0f);
}

// ---------------------------------------------------------------------------
// FC2: h2[32,32] = relu(h1[32,1024] @ fw2[32,1024]^T + fb2). One block per m.
// ---------------------------------------------------------------------------
__global__ __launch_bounds__(256) void fc2_k(
    const float* __restrict__ h1, const float* __restrict__ fw2,
    const float* __restrict__ fb2, float* __restrict__ h2)
{
    __shared__ float hs[1024];
    const int m = blockIdx.x;
    const int tid = threadIdx.x;
    for (int i = tid; i < 1024; i += 256) hs[i] = h1[m * 1024 + i];
    __syncthreads();
    const int wave = tid >> 6, lane = tid & 63;
#pragma unroll 1
    for (int nn = 0; nn < 8; ++nn) {
        int n = wave * 8 + nn;
        float p = 0.0f;
        for (int k = lane; k < 1024; k += 64)
            p += fw2[n * 1024 + k] * hs[k];
#pragma unroll
        for (int off = 32; off; off >>= 1) p += __shfl_xor(p, off);
        if (lane == 0) h2[m * 32 + n] = fmaxf(p + fb2[n], 0.0f);
    }
}

// ---------------------------------------------------------------------------
// FC3 + theta construction. 128 threads = 32 batches x 4 outputs.
// ---------------------------------------------------------------------------
__global__ void fc3_theta_k(
    const float* __restrict__ h2, const float* __restrict__ fw3,
    const float* __restrict__ fb3, float* __restrict__ theta_out)
{
    int t = threadIdx.x;
    if (t >= 128) return;
    int m = t >> 2, j = t & 3;
    float s = fb3[j];
#pragma unroll
    for (int k = 0; k < 32; ++k) s += h2[m * 32 + k] * fw3[j * 32 + k];
    float* th = theta_out + m * 6;
    if (j == 0)      { th[0] = 1.0f / (1.0f + expf(-s)); th[1] = 0.0f; }
    else if (j == 1) { th[4] = 1.0f / (1.0f + expf(-s)); th[3] = 0.0f; }
    else if (j == 2) { th[2] = tanhf(s); }
    else             { th[5] = tanhf(s); }
}

// ---------------------------------------------------------------------------
// Bilinear grid-sample, padding_mode='zeros', align_corners=False. C=1.
// ---------------------------------------------------------------------------
__global__ __launch_bounds__(256) void sampler_k(
    const float* __restrict__ im, const float* __restrict__ theta,
    float* __restrict__ out)
{
    int idx = blockIdx.x * 256 + threadIdx.x;
    int x = idx & 255;
    int y = (idx >> 8) & 255;
    int b = idx >> 16;
    const float* th = theta + b * 6;
    float xsn = (2.0f * x + 1.0f) * (1.0f / 256.0f) - 1.0f;
    float ysn = (2.0f * y + 1.0f) * (1.0f / 256.0f) - 1.0f;
    float gx = th[0] * xsn + th[1] * ysn + th[2];
    float gy = th[3] * xsn + th[4] * ysn + th[5];
    float ix = ((gx + 1.0f) * 256.0f - 1.0f) * 0.5f;
    float iy = ((gy + 1.0f) * 256.0f - 1.0f) * 0.5f;
    float x0 = floorf(ix), y0 = floorf(iy);
    float wx1 = ix - x0, wy1 = iy - y0;
    float wx0 = 1.0f - wx1, wy0 = 1.0f - wy1;
    const float* src = im + (size_t)b * 65536;

    auto g = [&](float xf, float yf) -> float {
        if (xf < 0.0f || xf > 255.0f || yf < 0.0f || yf > 255.0f) return 0.0f;
        int xi = (int)xf, yi = (int)yf;
        return src[yi * 256 + xi];
    };
    float v00 = g(x0, y0);
    float v10 = g(x0 + 1.0f, y0);
    float v01 = g(x0, y0 + 1.0f);
    float v11 = g(x0 + 1.0f, y0 + 1.0f);
    out[idx] = v00 * wx0 * wy0 + v10 * wx1 * wy0 + v01 * wx0 * wy1 + v11 * wx1 * wy1;
}

// ---------------------------------------------------------------------------
// Workspace layout (floats), peak 15,466,496 floats = 61.9 MB (verified):
//   x2   @ 0          (4,194,304)   32x8x128x128
//   x1c  @ 4,194,304  (8,388,608)   conv1 out, 16-batch chunk
//   x3   @ 4,194,304  (8,388,608)   32x16x128x128  (x1c dead after conv2)
//   x4   @ 12,582,912 (2,097,152)   32x16x64x64
//   x5   @ 4,194,304  (3,145,728)   32x24x64x64    (x3 dead after conv4)
//   x6   @ 14,680,064 (786,432)     32x24x32x32
//   part @ 0          (1,048,576)   split-K partials (x2 dead after conv4)
//   h1   @ 1,048,576  (32,768)
//   h2   @ 1,081,344  (1,024)
// ---------------------------------------------------------------------------
extern "C" void kernel_launch(void* const* d_in, const int* in_sizes, int n_in,
                              void* d_out, int out_size, void* d_ws, size_t ws_size,
                              hipStream_t stream)
{
    const float* im  = (const float*)d_in[0];
    const float* w1  = (const float*)d_in[1];  const float* b1 = (const float*)d_in[2];
    const float* w2  = (const float*)d_in[3];  const float* b2 = (const float*)d_in[4];
    const float* w3  = (const float*)d_in[5];  const float* b3 = (const float*)d_in[6];
    const float* w4  = (const float*)d_in[7];  const float* b4 = (const float*)d_in[8];
    const float* w5  = (const float*)d_in[9];  const float* b5 = (const float*)d_in[10];
    const float* w6  = (const float*)d_in[11]; const float* b6 = (const float*)d_in[12];
    const float* fw1 = (const float*)d_in[13]; const float* fb1 = (const float*)d_in[14];
    const float* fw2 = (const float*)d_in[15]; const float* fb2 = (const float*)d_in[16];
    const float* fw3 = (const float*)d_in[17]; const float* fb3 = (const float*)d_in[18];

    float* out = (float*)d_out;
    float* ws  = (float*)d_ws;

    float* x2   = ws + 0;
    float* x1c  = ws + 4194304;
    float* x3   = ws + 4194304;
    float* x4   = ws + 12582912;
    float* x5   = ws + 4194304;
    float* x6   = ws + 14680064;
    float* part = ws + 0;
    float* h1   = ws + 1048576;
    float* h2   = ws + 1081344;

    float* theta = out + 32 * 65536;

    // conv1 + conv2, chunked over batch (2 x 16) to bound workspace
    for (int c = 0; c < 2; ++c) {
        const float* imc = im + (size_t)c * 16 * 65536;
        // <CIN1,CIN2,COUT,CG,STRIDE,CCH>  grid = B*tpc*tpr*NG
        convg_k<1, 0, 8, 8, 1, 1><<<16 * 16 * 16, 256, 0, stream>>>(
            imc, nullptr, w1, b1, x1c, 256, 256);
        convg_k<8, 1, 8, 8, 2, 1><<<16 * 8 * 8, 256, 0, stream>>>(
            x1c, imc, w2, b2, x2 + (size_t)c * 2097152, 256, 256);
    }
    convg_k<8, 0, 16, 8, 1, 2><<<32 * 8 * 8 * 2, 256, 0, stream>>>(
        x2, nullptr, w3, b3, x3, 128, 128);
    convg_k<16, 8, 16, 8, 2, 1><<<32 * 4 * 4 * 2, 256, 0, stream>>>(
        x3, x2, w4, b4, x4, 128, 128);
    convg_k<16, 0, 24, 8, 1, 2><<<32 * 4 * 4 * 3, 256, 0, stream>>>(
        x4, nullptr, w5, b5, x5, 64, 64);
    convg_k<24, 16, 24, 4, 2, 1><<<32 * 2 * 2 * 6, 256, 0, stream>>>(
        x5, x4, w6, b6, x6, 64, 64);

    // FC stack
    fc1_stage_k<<<dim3(16, FC1_KS), 256, 0, stream>>>(x6, fw1, part);
    fc1_reduce_k<<<128, 256, 0, stream>>>(part, fb1, h1);
    fc2_k<<<32, 256, 0, stream>>>(h1, fw2, fb2, h2);
    fc3_theta_k<<<1, 128, 0, stream>>>(h2, fw3, fb3, theta);

    // grid sample from theta (written into d_out tail, stream-ordered)
    sampler_k<<<8192, 256, 0, stream>>>(im, theta, out);
}